// Round 15
// baseline (2115.092 us; speedup 1.0000x reference)
//
#include <hip/hip_runtime.h>
#include <math.h>

// BiometricLSTM: 2-layer LSTM, B=512, T=2048, I=3, H=64, fp32 in/out. Output = final h2 (B,64).
//
// R15: R13's split-wave MFMA structure at 1 seq/block -> 512 blocks -> 2 blocks/CU
// -> 4 waves/SIMD. R14 (merged waves, 1 wave/SIMD) regressed because the whole
// per-iter chain ran latency-exposed; R13 was faster purely from 2 waves/SIMD of
// mutual hiding (R5->R6 mechanism, m114). This doubles the resident independent
// work again. M=1: the seq is replicated across all 16 MFMA rows (A-row addr 0):
// A-frags are 16B wave-broadcasts (free), and all C/D regs hold the same value ->
// no sel4 (read reg 0). Waves 0-3 = L0 (8 MFMA, 16 cols each), waves 4-7 = L1
// (16 MFMA). Lane (quad 0, l16) writes h. Same parity/lag-1 pipeline and f16
// fragment conventions as R12-R14 (proven; absmax bit-identical expected).

typedef _Float16 half8 __attribute__((ext_vector_type(8)));
typedef float    f32x4 __attribute__((ext_vector_type(4)));

constexpr int TT = 2048;

__device__ __forceinline__ float fast_sigmoid(float x) {
    return 1.0f / (1.0f + __expf(-x));
}
// tanh = 1 - 2/(exp(2x)+1): saturates correctly at +-inf
__device__ __forceinline__ float fast_tanh(float x) {
    return 1.0f - 2.0f / (__expf(2.0f * x) + 1.0f);
}

__global__ __launch_bounds__(512) void lstm2_fused(
    const float* __restrict__ x,
    const float* __restrict__ Wih0, const float* __restrict__ Whh0,
    const float* __restrict__ bih0, const float* __restrict__ bhh0,
    const float* __restrict__ Wih1, const float* __restrict__ Whh1,
    const float* __restrict__ bih1, const float* __restrict__ bhh1,
    float* __restrict__ out)
{
    __shared__ __align__(16) _Float16 h1a[2][64];   // [parity][elem], single seq
    __shared__ __align__(16) _Float16 h2a[2][64];

    const int tid  = threadIdx.x;
    const int lane = tid & 63;
    const int wid  = tid >> 6;
    const int quad = lane >> 4;
    const int l16  = lane & 15;
    const bool isL1 = (wid >= 4);
    const int col  = (wid & 3) * 16 + l16;   // gate-elem column this lane owns per class

    // ---- zero h double-buffers (256 halves) ----
    if (tid < 256) {
        ((_Float16*)h1a)[tid & 127] = (_Float16)0.0f;      // covers h1a[0..1]
        ((_Float16*)h2a)[tid & 127] = (_Float16)0.0f;      // (redundant x2, benign)
    }

    // ---- weights (B-fragments, f16): lane holds W[c*64+col][f*32 + quad*8 .. +8] ----
    half8 wfr[4][4];                         // [class][kfrag]; L0 uses 0..1
    float bias[4];
    float wxa[4], wxb[4], wxc[4];            // L0 only
    #pragma unroll
    for (int c = 0; c < 4; ++c) {
        const int row = c * 64 + col;
        if (!isL1) {
            #pragma unroll
            for (int f = 0; f < 2; ++f) {
                const float* p = Whh0 + (size_t)row * 64 + f * 32 + quad * 8;
                half8 h;
                #pragma unroll
                for (int u = 0; u < 8; ++u) h[u] = (_Float16)p[u];
                wfr[c][f] = h;
            }
            bias[c] = bih0[row] + bhh0[row];
            wxa[c] = Wih0[row*3+0]; wxb[c] = Wih0[row*3+1]; wxc[c] = Wih0[row*3+2];
        } else {
            #pragma unroll
            for (int f = 0; f < 4; ++f) {
                const float* base = (f < 2) ? Wih1 : Whh1;
                const float* p = base + (size_t)row * 64 + (f & 1) * 32 + quad * 8;
                half8 h;
                #pragma unroll
                for (int u = 0; u < 8; ++u) h[u] = (_Float16)p[u];
                wfr[c][f] = h;
            }
            bias[c] = bih1[row] + bhh1[row];
        }
    }

    // ---- x prefetch (L0 waves): single seq = blockIdx; all lanes same addr (bcast) ----
    const float* xq = x + (size_t)blockIdx.x * TT * 3;
    float xn0 = 0.f, xn1 = 0.f, xn2 = 0.f;
    if (!isL1) { xn0 = xq[0]; xn1 = xq[1]; xn2 = xq[2]; }

    float cst = 0.0f;                        // cell state (layer per role, elem col)

    __syncthreads();

    // iter it: L0 computes step it (it<TT); L1 computes step it-1 (it>=1).
    // h1[t], h2[t] live at parity t&1. ONE barrier per iteration. (R12-proven.)
    for (int it = 0; it <= TT; ++it) {
        const int cur  = it & 1;
        const int prev = cur ^ 1;

        if (!isL1) {
            if (it < TT) {
                const float x0 = xn0, x1 = xn1, x2 = xn2;
                const int nt = (it + 1 < TT) ? it + 1 : TT - 1;
                const float* np = xq + nt * 3;
                xn0 = np[0]; xn1 = np[1]; xn2 = np[2];

                // A-frags: row 0 (seq replicated), k = f*32 + quad*8 -> 16B broadcast
                const _Float16* hb = h1a[prev] + quad * 8;
                half8 a0 = *(const half8*)hb;
                half8 a1 = *(const half8*)(hb + 32);
                f32x4 acc[4];
                #pragma unroll
                for (int c = 0; c < 4; ++c) {
                    f32x4 z = {0.f, 0.f, 0.f, 0.f};
                    z = __builtin_amdgcn_mfma_f32_16x16x32_f16(a0, wfr[c][0], z, 0, 0, 0);
                    z = __builtin_amdgcn_mfma_f32_16x16x32_f16(a1, wfr[c][1], z, 0, 0, 0);
                    acc[c] = z;
                }
                // all C/D regs identical (replicated rows) -> read reg 0
                float pi = acc[0][0] + bias[0] + wxa[0]*x0 + wxb[0]*x1 + wxc[0]*x2;
                float pf = acc[1][0] + bias[1] + wxa[1]*x0 + wxb[1]*x1 + wxc[1]*x2;
                float pg = acc[2][0] + bias[2] + wxa[2]*x0 + wxb[2]*x1 + wxc[2]*x2;
                float po = acc[3][0] + bias[3] + wxa[3]*x0 + wxb[3]*x1 + wxc[3]*x2;
                float iv = fast_sigmoid(pi), fv = fast_sigmoid(pf);
                float gv = fast_tanh(pg),    ov = fast_sigmoid(po);
                cst = fmaf(fv, cst, iv * gv);
                if (quad == 0)
                    h1a[cur][col] = (_Float16)(ov * fast_tanh(cst));   // h1[it]
            }
        } else {
            if (it >= 1) {
                // L1 step it-1: K 0..63 = h1[it-1] (parity prev); 64..127 = h2[it-2] (parity cur)
                const _Float16* hb1 = h1a[prev] + quad * 8;
                const _Float16* hb2 = h2a[cur]  + quad * 8;
                half8 a0 = *(const half8*)hb1;
                half8 a1 = *(const half8*)(hb1 + 32);
                half8 a2 = *(const half8*)hb2;
                half8 a3 = *(const half8*)(hb2 + 32);
                f32x4 acc[4];
                #pragma unroll
                for (int c = 0; c < 4; ++c) {
                    f32x4 z = {0.f, 0.f, 0.f, 0.f};
                    z = __builtin_amdgcn_mfma_f32_16x16x32_f16(a0, wfr[c][0], z, 0, 0, 0);
                    z = __builtin_amdgcn_mfma_f32_16x16x32_f16(a1, wfr[c][1], z, 0, 0, 0);
                    z = __builtin_amdgcn_mfma_f32_16x16x32_f16(a2, wfr[c][2], z, 0, 0, 0);
                    z = __builtin_amdgcn_mfma_f32_16x16x32_f16(a3, wfr[c][3], z, 0, 0, 0);
                    acc[c] = z;
                }
                float pi = acc[0][0] + bias[0];
                float pf = acc[1][0] + bias[1];
                float pg = acc[2][0] + bias[2];
                float po = acc[3][0] + bias[3];
                float iv = fast_sigmoid(pi), fv = fast_sigmoid(pf);
                float gv = fast_tanh(pg),    ov = fast_sigmoid(po);
                cst = fmaf(fv, cst, iv * gv);
                float hv = ov * fast_tanh(cst);
                if (quad == 0) {
                    h2a[prev][col] = (_Float16)hv;                     // h2[it-1]
                    if (it == TT)
                        out[(size_t)blockIdx.x * 64 + col] = hv;
                }
            }
        }
        __syncthreads();
    }
}

extern "C" void kernel_launch(void* const* d_in, const int* in_sizes, int n_in,
                              void* d_out, int out_size, void* d_ws, size_t ws_size,
                              hipStream_t stream) {
    const float* x    = (const float*)d_in[0];
    const float* Wih0 = (const float*)d_in[1];
    const float* Whh0 = (const float*)d_in[2];
    const float* bih0 = (const float*)d_in[3];
    const float* bhh0 = (const float*)d_in[4];
    const float* Wih1 = (const float*)d_in[5];
    const float* Whh1 = (const float*)d_in[6];
    const float* bih1 = (const float*)d_in[7];
    const float* bhh1 = (const float*)d_in[8];
    float* out = (float*)d_out;

    // 512 sequences, 1 per block -> 512 blocks = 2 blocks/CU; 512 threads
    // (8 waves) -> 4 waves/SIMD of independent work for latency hiding.
    lstm2_fused<<<512, 512, 0, stream>>>(x, Wih0, Whh0, bih0, bhh0,
                                         Wih1, Whh1, bih1, bhh1, out);
}